// Round 1
// baseline (440.323 us; speedup 1.0000x reference)
//
#include <hip/hip_runtime.h>
#include <math.h>

#define HID 16
#define KNN 16
#define NB 64          // graphs
#define NTS 8192
#define NLC 12288
#define TSG 128        // ts rows per graph
#define LCG 192        // lc rows per graph

__device__ __forceinline__ float eluf(float x) {
    return x > 0.0f ? x : expm1f(x);
}

// ---------------------------------------------------------------- encoders
__global__ void encode_kernel(
    const float* __restrict__ x_ts, const float* __restrict__ x_lc,
    const float* __restrict__ ts_w1, const float* __restrict__ ts_b1,
    const float* __restrict__ ts_w2, const float* __restrict__ ts_b2,
    const float* __restrict__ lc_w1, const float* __restrict__ lc_b1,
    const float* __restrict__ lc_w2, const float* __restrict__ lc_b2,
    float* __restrict__ ts_enc, float* __restrict__ lc_enc)
{
    int t = blockIdx.x * blockDim.x + threadIdx.x;
    const float *x, *w1, *b1, *w2, *b2;
    float* outp;
    int in_dim;
    if (t < NTS) {
        x = x_ts + t * 6; w1 = ts_w1; b1 = ts_b1; w2 = ts_w2; b2 = ts_b2;
        outp = ts_enc + t * HID; in_dim = 6;
    } else if (t < NTS + NLC) {
        int r = t - NTS;
        x = x_lc + r * 5; w1 = lc_w1; b1 = lc_b1; w2 = lc_w2; b2 = lc_b2;
        outp = lc_enc + r * HID; in_dim = 5;
    } else {
        return;
    }
    float xin[6];
    for (int k = 0; k < in_dim; ++k) xin[k] = x[k];
    float h[HID];
    #pragma unroll
    for (int c = 0; c < HID; ++c) {
        float s = b1[c];
        for (int k = 0; k < in_dim; ++k) s += xin[k] * w1[k * HID + c];
        h[c] = eluf(s);
    }
    #pragma unroll
    for (int c = 0; c < HID; ++c) {
        float s = b2[c];
        #pragma unroll
        for (int k = 0; k < HID; ++k) s += h[k] * w2[k * HID + c];
        outp[c] = eluf(s);
    }
}

// ------------------------------------------------------------ edge conv
// One block per graph. src rows contiguous [g*NSRC, (g+1)*NSRC), dst rows
// contiguous [g*NDST, (g+1)*NDST). One thread per dst row.
// Message nn([xi, xj-xi]) = b + xi@(W1-W2) + xj@W2; the xj@W2 half is
// dst-independent so we precompute it per src row once per block.
template<int NSRC, int NDST, bool POOL>
__global__ __launch_bounds__(NDST) void edgeconv_kernel(
    const float* __restrict__ src, const float* __restrict__ dst,
    const float* __restrict__ cw, const float* __restrict__ cb,
    float* __restrict__ out_feats, float* __restrict__ pool_out)
{
    constexpr int LDW = HID + 1;  // stride 17: breaks idx*16 -> 2-bank conflicts
    __shared__ float s_src[NSRC * LDW];
    __shared__ float s_y[NSRC * LDW];     // src @ W2
    __shared__ float s_norm[NSRC];
    __shared__ float s_w[2 * HID * HID];
    __shared__ float s_b[HID];

    const int g = blockIdx.x;
    const int tid = threadIdx.x;

    // stage src rows + norms
    for (int i = tid; i < NSRC; i += NDST) {
        const float4* r4 = reinterpret_cast<const float4*>(src + (size_t)(g * NSRC + i) * HID);
        float4 v0 = r4[0], v1 = r4[1], v2 = r4[2], v3 = r4[3];
        float* srow = &s_src[i * LDW];
        srow[0] = v0.x; srow[1] = v0.y; srow[2]  = v0.z; srow[3]  = v0.w;
        srow[4] = v1.x; srow[5] = v1.y; srow[6]  = v1.z; srow[7]  = v1.w;
        srow[8] = v2.x; srow[9] = v2.y; srow[10] = v2.z; srow[11] = v2.w;
        srow[12] = v3.x; srow[13] = v3.y; srow[14] = v3.z; srow[15] = v3.w;
        float n = 0.f;
        #pragma unroll
        for (int c = 0; c < HID; ++c) n += srow[c] * srow[c];
        s_norm[i] = n;
    }
    for (int i = tid; i < 2 * HID * HID; i += NDST) s_w[i] = cw[i];
    if (tid < HID) s_b[tid] = cb[tid];
    __syncthreads();

    // y = src @ W2 (cooperative, once per block)
    for (int i = tid; i < NSRC; i += NDST) {
        float xr[HID];
        #pragma unroll
        for (int r = 0; r < HID; ++r) xr[r] = s_src[i * LDW + r];
        #pragma unroll
        for (int c = 0; c < HID; ++c) {
            float s = 0.f;
            #pragma unroll
            for (int r = 0; r < HID; ++r) s += xr[r] * s_w[(HID + r) * HID + c];
            s_y[i * LDW + c] = s;
        }
    }

    // my query row
    float xi[HID];
    float nd = 0.f;
    {
        const float4* r4 = reinterpret_cast<const float4*>(dst + (size_t)(g * NDST + tid) * HID);
        float4 v0 = r4[0], v1 = r4[1], v2 = r4[2], v3 = r4[3];
        xi[0] = v0.x; xi[1] = v0.y; xi[2]  = v0.z; xi[3]  = v0.w;
        xi[4] = v1.x; xi[5] = v1.y; xi[6]  = v1.z; xi[7]  = v1.w;
        xi[8] = v2.x; xi[9] = v2.y; xi[10] = v2.z; xi[11] = v2.w;
        xi[12] = v3.x; xi[13] = v3.y; xi[14] = v3.z; xi[15] = v3.w;
        #pragma unroll
        for (int c = 0; c < HID; ++c) nd += xi[c] * xi[c];
    }
    __syncthreads();

    // top-16 smallest d2, ties -> lower index (strict < => later equal excluded)
    float bd[KNN];
    int   bix[KNN];
    #pragma unroll
    for (int p = 0; p < KNN; ++p) { bd[p] = __builtin_inff(); bix[p] = 0; }
    for (int j = 0; j < NSRC; ++j) {
        const float* row = &s_src[j * LDW];
        float dot = 0.f;
        #pragma unroll
        for (int c = 0; c < HID; ++c) dot += xi[c] * row[c];
        float d = nd - 2.0f * dot + s_norm[j];
        if (d < bd[KNN - 1]) {
            bd[KNN - 1] = d;
            bix[KNN - 1] = j;
            #pragma unroll
            for (int p = KNN - 1; p > 0; --p) {
                if (bd[p - 1] > bd[p]) {
                    float td = bd[p - 1]; bd[p - 1] = bd[p]; bd[p] = td;
                    int ti = bix[p - 1]; bix[p - 1] = bix[p]; bix[p] = ti;
                }
            }
        }
    }

    // ci = b + xi @ (W1 - W2)
    float ci[HID];
    #pragma unroll
    for (int c = 0; c < HID; ++c) {
        float s = s_b[c];
        #pragma unroll
        for (int r = 0; r < HID; ++r)
            s += xi[r] * (s_w[r * HID + c] - s_w[(HID + r) * HID + c]);
        ci[c] = s;
    }

    // max over neighbors of elu(ci + y[j])
    float acc[HID];
    #pragma unroll
    for (int c = 0; c < HID; ++c) acc[c] = -__builtin_inff();
    #pragma unroll
    for (int n = 0; n < KNN; ++n) {
        const float* yrow = &s_y[bix[n] * LDW];
        #pragma unroll
        for (int c = 0; c < HID; ++c) {
            float m = eluf(ci[c] + yrow[c]);
            acc[c] = fmaxf(acc[c], m);
        }
    }

    if (!POOL) {
        float* orow = out_feats + (size_t)(g * NDST + tid) * HID;
        #pragma unroll
        for (int c = 0; c < HID; ++c) orow[c] = acc[c];
    } else {
        __syncthreads();  // done reading s_src; reuse it for the pool
        #pragma unroll
        for (int c = 0; c < HID; ++c) s_src[tid * LDW + c] = acc[c];
        __syncthreads();
        if (tid < HID) {
            float s = 0.f;
            for (int t = 0; t < NDST; ++t) s += s_src[t * LDW + tid];
            pool_out[g * HID + tid] = s * (1.0f / (float)NDST);
        }
    }
}

// ---------------------------------------------------------------- head MLP
__global__ __launch_bounds__(NB) void head_kernel(
    const float* __restrict__ pooled,
    const float* __restrict__ w1, const float* __restrict__ b1,
    const float* __restrict__ w2, const float* __restrict__ b2,
    const float* __restrict__ w3, const float* __restrict__ b3,
    const float* __restrict__ w4, const float* __restrict__ b4,
    const float* __restrict__ w5, const float* __restrict__ b5,
    float* __restrict__ out)
{
    int gidx = threadIdx.x;  // one thread per graph
    float p[HID];
    #pragma unroll
    for (int c = 0; c < HID; ++c) p[c] = pooled[gidx * HID + c];

    float h1[64];
    #pragma unroll
    for (int o = 0; o < 64; ++o) {
        float s = b1[o];
        #pragma unroll
        for (int r = 0; r < HID; ++r) s += p[r] * w1[r * 64 + o];
        h1[o] = eluf(s);
    }
    float h2[32];
    #pragma unroll
    for (int o = 0; o < 32; ++o) {
        float s = b2[o];
        #pragma unroll
        for (int r = 0; r < 64; ++r) s += h1[r] * w2[r * 32 + o];
        h2[o] = eluf(s);
    }
    float h3[8];
    #pragma unroll
    for (int o = 0; o < 8; ++o) {
        float s = b3[o];
        #pragma unroll
        for (int r = 0; r < 32; ++r) s += h2[r] * w3[r * 8 + o];
        h3[o] = eluf(s);
    }
    float h4[4];
    #pragma unroll
    for (int o = 0; o < 4; ++o) {
        float s = b4[o];
        #pragma unroll
        for (int r = 0; r < 8; ++r) s += h3[r] * w4[r * 4 + o];
        h4[o] = eluf(s);
    }
    float o5 = b5[0];
    #pragma unroll
    for (int r = 0; r < 4; ++r) o5 += h4[r] * w5[r];

    out[gidx] = o5;
    out[NB + gidx] = (float)gidx;  // batch_out = arange(B)
}

// ---------------------------------------------------------------- launch
extern "C" void kernel_launch(void* const* d_in, const int* in_sizes, int n_in,
                              void* d_out, int out_size, void* d_ws, size_t ws_size,
                              hipStream_t stream) {
    const float* x_ts  = (const float*)d_in[0];
    const float* x_lc  = (const float*)d_in[1];
    // d_in[2], d_in[3]: batch arrays — contiguous repeat(arange(64)), layout hard-coded
    const float* ts_w1 = (const float*)d_in[4];
    const float* ts_b1 = (const float*)d_in[5];
    const float* ts_w2 = (const float*)d_in[6];
    const float* ts_b2 = (const float*)d_in[7];
    const float* lc_w1 = (const float*)d_in[8];
    const float* lc_b1 = (const float*)d_in[9];
    const float* lc_w2 = (const float*)d_in[10];
    const float* lc_b2 = (const float*)d_in[11];
    const float* cw    = (const float*)d_in[12];
    const float* cb    = (const float*)d_in[13];
    const float* ow1   = (const float*)d_in[14];
    const float* ob1   = (const float*)d_in[15];
    const float* ow2   = (const float*)d_in[16];
    const float* ob2   = (const float*)d_in[17];
    const float* ow3   = (const float*)d_in[18];
    const float* ob3   = (const float*)d_in[19];
    const float* ow4   = (const float*)d_in[20];
    const float* ob4   = (const float*)d_in[21];
    const float* ow5   = (const float*)d_in[22];
    const float* ob5   = (const float*)d_in[23];
    float* out = (float*)d_out;

    float* ws = (float*)d_ws;
    float* ts_enc = ws;                       // 8192*16  = 131072
    float* lc_enc = ws + 131072;              // 12288*16 = 196608
    float* feats1 = ws + 327680;              // 12288*16 = 196608
    float* feats2 = ws + 524288;              // 8192*16  = 131072
    float* pooled = ws + 655360;              // 64*16    = 1024

    encode_kernel<<<(NTS + NLC + 255) / 256, 256, 0, stream>>>(
        x_ts, x_lc, ts_w1, ts_b1, ts_w2, ts_b2, lc_w1, lc_b1, lc_w2, lc_b2,
        ts_enc, lc_enc);

    // feats1: lc -> lc
    edgeconv_kernel<LCG, LCG, false><<<NB, LCG, 0, stream>>>(
        lc_enc, lc_enc, cw, cb, feats1, nullptr);
    // feats2: lc src, ts dst
    edgeconv_kernel<LCG, TSG, false><<<NB, TSG, 0, stream>>>(
        lc_enc, ts_enc, cw, cb, feats2, nullptr);
    // feats3: feats1 src, feats2 dst, fused mean-pool
    edgeconv_kernel<LCG, TSG, true><<<NB, TSG, 0, stream>>>(
        feats1, feats2, cw, cb, nullptr, pooled);

    head_kernel<<<1, NB, 0, stream>>>(
        pooled, ow1, ob1, ow2, ob2, ow3, ob3, ow4, ob4, ow5, ob5, out);
}

// Round 2
// 259.979 us; speedup vs baseline: 1.6937x; 1.6937x over previous
//
#include <hip/hip_runtime.h>
#include <math.h>

#define HID 16
#define KNN 16
#define NB 64          // graphs
#define NTS 8192
#define NLC 12288
#define TSG 128        // ts rows per graph
#define LCG 192        // lc rows per graph

__device__ __forceinline__ float eluf(float x) {
    return x > 0.0f ? x : expm1f(x);
}

// ---------------------------------------------------------------- encoders
// Also zeroes `pooled` (re-poisoned to 0xAA before every launch) so the
// conv3 atomics land on 0.
__global__ void encode_kernel(
    const float* __restrict__ x_ts, const float* __restrict__ x_lc,
    const float* __restrict__ ts_w1, const float* __restrict__ ts_b1,
    const float* __restrict__ ts_w2, const float* __restrict__ ts_b2,
    const float* __restrict__ lc_w1, const float* __restrict__ lc_b1,
    const float* __restrict__ lc_w2, const float* __restrict__ lc_b2,
    float* __restrict__ ts_enc, float* __restrict__ lc_enc,
    float* __restrict__ pooled)
{
    int t = blockIdx.x * blockDim.x + threadIdx.x;
    if (t < NB * HID) pooled[t] = 0.0f;   // 1024 floats

    const float *x, *w1, *b1, *w2, *b2;
    float* outp;
    int in_dim;
    if (t < NTS) {
        x = x_ts + t * 6; w1 = ts_w1; b1 = ts_b1; w2 = ts_w2; b2 = ts_b2;
        outp = ts_enc + t * HID; in_dim = 6;
    } else if (t < NTS + NLC) {
        int r = t - NTS;
        x = x_lc + r * 5; w1 = lc_w1; b1 = lc_b1; w2 = lc_w2; b2 = lc_b2;
        outp = lc_enc + r * HID; in_dim = 5;
    } else {
        return;
    }
    float xin[6];
    for (int k = 0; k < in_dim; ++k) xin[k] = x[k];
    float h[HID];
    #pragma unroll
    for (int c = 0; c < HID; ++c) {
        float s = b1[c];
        for (int k = 0; k < in_dim; ++k) s += xin[k] * w1[k * HID + c];
        h[c] = eluf(s);
    }
    #pragma unroll
    for (int c = 0; c < HID; ++c) {
        float s = b2[c];
        #pragma unroll
        for (int k = 0; k < HID; ++k) s += h[k] * w2[k * HID + c];
        outp[c] = eluf(s);
    }
}

// ------------------------------------------------------------ edge conv
// ONE WAVE PER DST ROW. Block = 512 threads = 8 waves = 8 dst rows of one
// graph; BLOCKS_PER_GRAPH = NDST/8 blocks re-stage the graph's 192 src rows
// (+ norms + y = src@W2, computed cooperatively) in LDS. Lane l owns src rows
// {l, l+64, l+128}; top-16 found by 16 rounds of wave-wide butterfly min
// extraction on (d, idx) lexicographic order (matches top_k tie-break set).
// Message nn([xi, xj-xi]) = b + xi@(W1-W2) + xj@W2, max over neighbors.
template<int NSRC, int NDST, bool POOL>
__global__ __launch_bounds__(512) void edgeconv_kernel(
    const float* __restrict__ src, const float* __restrict__ dst,
    const float* __restrict__ cw, const float* __restrict__ cb,
    float* __restrict__ out_feats, float* __restrict__ pool_out)
{
    constexpr int LDW = HID + 1;        // stride 17: conflict-free lane strides
    constexpr int RPB = 8;              // dst rows (waves) per block
    constexpr int BPG = NDST / RPB;     // blocks per graph
    __shared__ float s_src[NSRC * LDW];
    __shared__ float s_y[NSRC * LDW];   // src @ W2
    __shared__ float s_norm[NSRC];
    __shared__ float s_w2[HID * HID];
    __shared__ float s_dw[HID * HID];   // W1 - W2
    __shared__ float s_b[HID];
    __shared__ float s_pool[HID];

    const int tid  = threadIdx.x;
    const int lane = tid & 63;
    const int wave = tid >> 6;
    const int g      = blockIdx.x / BPG;
    const int rowblk = blockIdx.x % BPG;

    // ---- phase 0: stage weights + src rows
    if (tid < HID * HID) {
        float w1v = cw[tid];
        float w2v = cw[HID * HID + tid];
        s_w2[tid] = w2v;
        s_dw[tid] = w1v - w2v;
    }
    if (tid < HID) s_b[tid] = cb[tid];
    if (POOL && tid < HID) s_pool[tid] = 0.0f;

    const float4* src4 = reinterpret_cast<const float4*>(src + (size_t)(g * NSRC) * HID);
    for (int idx = tid; idx < NSRC * 4; idx += 512) {
        float4 v = src4[idx];
        float* p = &s_src[(idx >> 2) * LDW + (idx & 3) * 4];
        p[0] = v.x; p[1] = v.y; p[2] = v.z; p[3] = v.w;
    }
    __syncthreads();

    // ---- phase 1: norms + y = src @ W2
    if (tid < NSRC) {
        float xr[HID];
        #pragma unroll
        for (int r = 0; r < HID; ++r) xr[r] = s_src[tid * LDW + r];
        float n = 0.f;
        #pragma unroll
        for (int c = 0; c < HID; ++c) n += xr[c] * xr[c];
        s_norm[tid] = n;
        #pragma unroll
        for (int c = 0; c < HID; ++c) {
            float s = 0.f;
            #pragma unroll
            for (int r = 0; r < HID; ++r) s += xr[r] * s_w2[r * HID + c];
            s_y[tid * LDW + c] = s;
        }
    }
    __syncthreads();

    // ---- phase 2: my wave's dst row
    const int drow = rowblk * RPB + wave;      // 0..NDST-1
    const float4* d4 = reinterpret_cast<const float4*>(dst + (size_t)(g * NDST + drow) * HID);
    float xi[HID];
    {
        float4 a = d4[0], b = d4[1], c4 = d4[2], e = d4[3];
        xi[0] = a.x;  xi[1] = a.y;  xi[2]  = a.z;  xi[3]  = a.w;
        xi[4] = b.x;  xi[5] = b.y;  xi[6]  = b.z;  xi[7]  = b.w;
        xi[8] = c4.x; xi[9] = c4.y; xi[10] = c4.z; xi[11] = c4.w;
        xi[12] = e.x; xi[13] = e.y; xi[14] = e.z;  xi[15] = e.w;
    }
    float nd = 0.f;
    #pragma unroll
    for (int c = 0; c < HID; ++c) nd += xi[c] * xi[c];

    // 3 candidates per lane: rows lane, lane+64, lane+128 (NSRC==192)
    float cd0, cd1, cd2;
    int   ci0, ci1, ci2;
    {
        float d[3];
        #pragma unroll
        for (int k = 0; k < 3; ++k) {
            const float* rp = &s_src[(lane + 64 * k) * LDW];
            float dot = 0.f;
            #pragma unroll
            for (int c = 0; c < HID; ++c) dot += xi[c] * rp[c];
            d[k] = nd - 2.0f * dot + s_norm[lane + 64 * k];
        }
        cd0 = d[0]; ci0 = lane;
        cd1 = d[1]; ci1 = lane + 64;
        cd2 = d[2]; ci2 = lane + 128;
        // sort 3 ascending by (d, idx); idx ascending pre-sort => strict < is stable-correct
        if (cd1 < cd0) { float t = cd0; cd0 = cd1; cd1 = t; int ti = ci0; ci0 = ci1; ci1 = ti; }
        if (cd2 < cd1) { float t = cd1; cd1 = cd2; cd2 = t; int ti = ci1; ci1 = ci2; ci2 = ti; }
        if (cd1 < cd0) { float t = cd0; cd0 = cd1; cd1 = t; int ti = ci0; ci0 = ci1; ci1 = ti; }
    }

    // 16 rounds of wave-wide min extraction -> nb[] wave-uniform in registers
    int nb[KNN];
    #pragma unroll
    for (int rnd = 0; rnd < KNN; ++rnd) {
        float wd = cd0;
        int   wi = ci0;
        #pragma unroll
        for (int off = 32; off > 0; off >>= 1) {
            float od = __shfl_xor(wd, off, 64);
            int   oi = __shfl_xor(wi, off, 64);
            bool take = (od < wd) || (od == wd && oi < wi);
            wd = take ? od : wd;
            wi = take ? oi : wi;
        }
        nb[rnd] = wi;
        bool own = ((wi & 63) == lane);   // winner is always the owner's head
        cd0 = own ? cd1 : cd0;  ci0 = own ? ci1 : ci0;
        cd1 = own ? cd2 : cd1;  ci1 = own ? ci2 : ci1;
        cd2 = own ? __builtin_inff() : cd2;
    }

    // ---- message + max-aggregate; lane handles channel c = lane&15
    const int c = lane & 15;
    float cic = s_b[c];
    #pragma unroll
    for (int r = 0; r < HID; ++r) cic += xi[r] * s_dw[r * HID + c];

    float acc = -__builtin_inff();
    #pragma unroll
    for (int n = 0; n < KNN; ++n) {
        float m = cic + s_y[nb[n] * LDW + c];
        m = m > 0.0f ? m : expm1f(m);
        acc = fmaxf(acc, m);
    }

    if (!POOL) {
        if (lane < HID)
            out_feats[(size_t)(g * NDST + drow) * HID + c] = acc;
    } else {
        if (lane < HID) atomicAdd(&s_pool[c], acc);
        __syncthreads();
        if (tid < HID) atomicAdd(&pool_out[g * HID + tid], s_pool[tid]);
    }
}

// ---------------------------------------------------------------- head MLP
__global__ __launch_bounds__(NB) void head_kernel(
    const float* __restrict__ pooled,   // SUMS over 128 rows per graph
    const float* __restrict__ w1, const float* __restrict__ b1,
    const float* __restrict__ w2, const float* __restrict__ b2,
    const float* __restrict__ w3, const float* __restrict__ b3,
    const float* __restrict__ w4, const float* __restrict__ b4,
    const float* __restrict__ w5, const float* __restrict__ b5,
    float* __restrict__ out)
{
    int gidx = threadIdx.x;  // one thread per graph
    float p[HID];
    #pragma unroll
    for (int c = 0; c < HID; ++c) p[c] = pooled[gidx * HID + c] * (1.0f / (float)TSG);

    float h1[64];
    #pragma unroll
    for (int o = 0; o < 64; ++o) {
        float s = b1[o];
        #pragma unroll
        for (int r = 0; r < HID; ++r) s += p[r] * w1[r * 64 + o];
        h1[o] = eluf(s);
    }
    float h2[32];
    #pragma unroll
    for (int o = 0; o < 32; ++o) {
        float s = b2[o];
        #pragma unroll
        for (int r = 0; r < 64; ++r) s += h1[r] * w2[r * 32 + o];
        h2[o] = eluf(s);
    }
    float h3[8];
    #pragma unroll
    for (int o = 0; o < 8; ++o) {
        float s = b3[o];
        #pragma unroll
        for (int r = 0; r < 32; ++r) s += h2[r] * w3[r * 8 + o];
        h3[o] = eluf(s);
    }
    float h4[4];
    #pragma unroll
    for (int o = 0; o < 4; ++o) {
        float s = b4[o];
        #pragma unroll
        for (int r = 0; r < 8; ++r) s += h3[r] * w4[r * 4 + o];
        h4[o] = eluf(s);
    }
    float o5 = b5[0];
    #pragma unroll
    for (int r = 0; r < 4; ++r) o5 += h4[r] * w5[r];

    out[gidx] = o5;
    out[NB + gidx] = (float)gidx;  // batch_out = arange(B)
}

// ---------------------------------------------------------------- launch
extern "C" void kernel_launch(void* const* d_in, const int* in_sizes, int n_in,
                              void* d_out, int out_size, void* d_ws, size_t ws_size,
                              hipStream_t stream) {
    const float* x_ts  = (const float*)d_in[0];
    const float* x_lc  = (const float*)d_in[1];
    // d_in[2], d_in[3]: batch arrays — contiguous repeat(arange(64)), layout hard-coded
    const float* ts_w1 = (const float*)d_in[4];
    const float* ts_b1 = (const float*)d_in[5];
    const float* ts_w2 = (const float*)d_in[6];
    const float* ts_b2 = (const float*)d_in[7];
    const float* lc_w1 = (const float*)d_in[8];
    const float* lc_b1 = (const float*)d_in[9];
    const float* lc_w2 = (const float*)d_in[10];
    const float* lc_b2 = (const float*)d_in[11];
    const float* cw    = (const float*)d_in[12];
    const float* cb    = (const float*)d_in[13];
    const float* ow1   = (const float*)d_in[14];
    const float* ob1   = (const float*)d_in[15];
    const float* ow2   = (const float*)d_in[16];
    const float* ob2   = (const float*)d_in[17];
    const float* ow3   = (const float*)d_in[18];
    const float* ob3   = (const float*)d_in[19];
    const float* ow4   = (const float*)d_in[20];
    const float* ob4   = (const float*)d_in[21];
    const float* ow5   = (const float*)d_in[22];
    const float* ob5   = (const float*)d_in[23];
    float* out = (float*)d_out;

    float* ws = (float*)d_ws;
    float* ts_enc = ws;                       // 8192*16  = 131072
    float* lc_enc = ws + 131072;              // 12288*16 = 196608
    float* feats1 = ws + 327680;              // 12288*16 = 196608
    float* feats2 = ws + 524288;              // 8192*16  = 131072
    float* pooled = ws + 655360;              // 64*16    = 1024

    encode_kernel<<<(NTS + NLC + 255) / 256, 256, 0, stream>>>(
        x_ts, x_lc, ts_w1, ts_b1, ts_w2, ts_b2, lc_w1, lc_b1, lc_w2, lc_b2,
        ts_enc, lc_enc, pooled);

    // feats1: lc -> lc   (64 graphs * 192/8 = 1536 blocks)
    edgeconv_kernel<LCG, LCG, false><<<NB * (LCG / 8), 512, 0, stream>>>(
        lc_enc, lc_enc, cw, cb, feats1, nullptr);
    // feats2: lc src, ts dst  (64 * 128/8 = 1024 blocks)
    edgeconv_kernel<LCG, TSG, false><<<NB * (TSG / 8), 512, 0, stream>>>(
        lc_enc, ts_enc, cw, cb, feats2, nullptr);
    // feats3: feats1 src, feats2 dst, fused mean-pool via atomics
    edgeconv_kernel<LCG, TSG, true><<<NB * (TSG / 8), 512, 0, stream>>>(
        feats1, feats2, cw, cb, nullptr, pooled);

    head_kernel<<<1, NB, 0, stream>>>(
        pooled, ow1, ob1, ow2, ob2, ow3, ob3, ow4, ob4, ow5, ob5, out);
}

// Round 3
// 206.139 us; speedup vs baseline: 2.1361x; 1.2612x over previous
//
#include <hip/hip_runtime.h>
#include <math.h>

#define HID 16
#define KNN 16
#define NB 64          // graphs
#define NTS 8192
#define NLC 12288
#define TSG 128        // ts rows per graph
#define LCG 192        // lc rows per graph

__device__ __forceinline__ float eluf(float x) {
    return x > 0.0f ? x : expm1f(x);
}

// ---------------------------------------------------------------- encoders
// Weights staged in LDS (coalesced, once per block) — the v2 kernel was
// SMEM-latency bound (uniform-address s_load chains at 0.3 waves/SIMD).
// Blocks 0..31 encode ts rows, 32..79 encode lc rows. Also zeroes `pooled`.
__global__ __launch_bounds__(256) void encode_kernel(
    const float* __restrict__ x_ts, const float* __restrict__ x_lc,
    const float* __restrict__ ts_w1, const float* __restrict__ ts_b1,
    const float* __restrict__ ts_w2, const float* __restrict__ ts_b2,
    const float* __restrict__ lc_w1, const float* __restrict__ lc_b1,
    const float* __restrict__ lc_w2, const float* __restrict__ lc_b2,
    float* __restrict__ ts_enc, float* __restrict__ lc_enc,
    float* __restrict__ pooled)
{
    __shared__ float sw1[6 * HID];
    __shared__ float sw2[HID * HID];
    __shared__ float sb1[HID];
    __shared__ float sb2[HID];

    const int tid = threadIdx.x;
    const int t = blockIdx.x * 256 + tid;
    if (t < NB * HID) pooled[t] = 0.0f;   // zero pool accumulator (0xAA-poisoned)

    const bool is_ts = (blockIdx.x < NTS / 256);
    const float* w1 = is_ts ? ts_w1 : lc_w1;
    const float* b1 = is_ts ? ts_b1 : lc_b1;
    const float* w2 = is_ts ? ts_w2 : lc_w2;
    const float* b2 = is_ts ? ts_b2 : lc_b2;
    const int in_dim = is_ts ? 6 : 5;

    if (tid < in_dim * HID) sw1[tid] = w1[tid];
    if (tid < HID * HID)    sw2[tid] = w2[tid];
    if (tid < HID)          { sb1[tid] = b1[tid]; sb2[tid] = b2[tid]; }
    __syncthreads();

    const float* x;
    float* outp;
    if (is_ts) { x = x_ts + (size_t)t * 6;          outp = ts_enc + (size_t)t * HID; }
    else       { int r = t - NTS; x = x_lc + (size_t)r * 5; outp = lc_enc + (size_t)r * HID; }

    float xin[6];
    for (int k = 0; k < in_dim; ++k) xin[k] = x[k];
    float h[HID];
    #pragma unroll
    for (int c = 0; c < HID; ++c) {
        float s = sb1[c];
        for (int k = 0; k < in_dim; ++k) s += xin[k] * sw1[k * HID + c];
        h[c] = eluf(s);
    }
    float o[HID];
    #pragma unroll
    for (int c = 0; c < HID; ++c) {
        float s = sb2[c];
        #pragma unroll
        for (int k = 0; k < HID; ++k) s += h[k] * sw2[k * HID + c];
        o[c] = eluf(s);
    }
    float4* o4 = reinterpret_cast<float4*>(outp);
    o4[0] = make_float4(o[0],  o[1],  o[2],  o[3]);
    o4[1] = make_float4(o[4],  o[5],  o[6],  o[7]);
    o4[2] = make_float4(o[8],  o[9],  o[10], o[11]);
    o4[3] = make_float4(o[12], o[13], o[14], o[15]);
}

// ------------------------------------------------------------ edge conv
// ONE WAVE PER DST ROW; block = 512 threads = 8 dst rows of one graph.
// Dynamic LDS so conv1+conv2 can share one fat-grid kernel (block-uniform
// branch) — they are independent and this removes a serialization point.
// Lane l owns src rows {l, l+64, l+128}; top-16 via 16 rounds of wave
// butterfly min-extraction on (d, idx) lexicographic order (= top_k set).
// Message nn([xi, xj-xi]) = b + xi@(W1-W2) + xj@W2 (xj half precomputed).
#define CONV_LDW (HID + 1)
#define CONV_SMEM_FLOATS (LCG * CONV_LDW * 2 + LCG + 2 * HID * HID + 2 * HID)
#define CONV_SMEM_BYTES (CONV_SMEM_FLOATS * 4)

template<int NSRC, int NDST, bool POOL>
__device__ __forceinline__ void edgeconv_impl(
    float* __restrict__ smem, int bid,
    const float* __restrict__ src, const float* __restrict__ dst,
    const float* __restrict__ cw, const float* __restrict__ cb,
    float* __restrict__ out_feats, float* __restrict__ pool_out)
{
    constexpr int LDW = CONV_LDW;
    constexpr int RPB = 8;              // dst rows (waves) per block
    constexpr int BPG = NDST / RPB;     // blocks per graph
    float* s_src  = smem;                        // NSRC*LDW
    float* s_y    = s_src + NSRC * LDW;          // NSRC*LDW
    float* s_norm = s_y + NSRC * LDW;            // NSRC
    float* s_w2   = s_norm + NSRC;               // 256
    float* s_dw   = s_w2 + HID * HID;            // 256  (W1 - W2)
    float* s_b    = s_dw + HID * HID;            // 16
    float* s_pool = s_b + HID;                   // 16

    const int tid  = threadIdx.x;
    const int lane = tid & 63;
    const int wave = tid >> 6;
    const int g      = bid / BPG;
    const int rowblk = bid % BPG;

    // ---- phase 0: stage weights + src rows (all vector/coalesced)
    if (tid < HID * HID) {
        float w1v = cw[tid];
        float w2v = cw[HID * HID + tid];
        s_w2[tid] = w2v;
        s_dw[tid] = w1v - w2v;
    }
    if (tid < HID) s_b[tid] = cb[tid];
    if (POOL && tid < HID) s_pool[tid] = 0.0f;

    const float4* src4 = reinterpret_cast<const float4*>(src + (size_t)(g * NSRC) * HID);
    for (int idx = tid; idx < NSRC * 4; idx += 512) {
        float4 v = src4[idx];
        float* p = &s_src[(idx >> 2) * LDW + (idx & 3) * 4];
        p[0] = v.x; p[1] = v.y; p[2] = v.z; p[3] = v.w;
    }
    __syncthreads();

    // ---- phase 1: norms + y = src @ W2 (384 half-rows: shorter critical path)
    if (tid < NSRC * 2) {
        const int row  = tid >> 1;
        const int half = (tid & 1) * 8;
        float xr[HID];
        #pragma unroll
        for (int r = 0; r < HID; ++r) xr[r] = s_src[row * LDW + r];
        if ((tid & 1) == 0) {
            float n = 0.f;
            #pragma unroll
            for (int c = 0; c < HID; ++c) n += xr[c] * xr[c];
            s_norm[row] = n;
        }
        #pragma unroll
        for (int c = 0; c < 8; ++c) {
            float s = 0.f;
            #pragma unroll
            for (int r = 0; r < HID; ++r) s += xr[r] * s_w2[r * HID + half + c];
            s_y[row * LDW + half + c] = s;
        }
    }
    __syncthreads();

    // ---- phase 2: my wave's dst row
    const int drow = rowblk * RPB + wave;
    const float4* d4 = reinterpret_cast<const float4*>(dst + (size_t)(g * NDST + drow) * HID);
    float xi[HID];
    {
        float4 a = d4[0], b = d4[1], c4 = d4[2], e = d4[3];
        xi[0] = a.x;  xi[1] = a.y;  xi[2]  = a.z;  xi[3]  = a.w;
        xi[4] = b.x;  xi[5] = b.y;  xi[6]  = b.z;  xi[7]  = b.w;
        xi[8] = c4.x; xi[9] = c4.y; xi[10] = c4.z; xi[11] = c4.w;
        xi[12] = e.x; xi[13] = e.y; xi[14] = e.z;  xi[15] = e.w;
    }
    float nd = 0.f;
    #pragma unroll
    for (int c = 0; c < HID; ++c) nd += xi[c] * xi[c];

    // 3 candidates per lane (NSRC == 192)
    float cd0, cd1, cd2;
    int   ci0, ci1, ci2;
    {
        float d[3];
        #pragma unroll
        for (int k = 0; k < 3; ++k) {
            const float* rp = &s_src[(lane + 64 * k) * LDW];
            float dot = 0.f;
            #pragma unroll
            for (int c = 0; c < HID; ++c) dot += xi[c] * rp[c];
            d[k] = nd - 2.0f * dot + s_norm[lane + 64 * k];
        }
        cd0 = d[0]; ci0 = lane;
        cd1 = d[1]; ci1 = lane + 64;
        cd2 = d[2]; ci2 = lane + 128;
        if (cd1 < cd0) { float t = cd0; cd0 = cd1; cd1 = t; int ti = ci0; ci0 = ci1; ci1 = ti; }
        if (cd2 < cd1) { float t = cd1; cd1 = cd2; cd2 = t; int ti = ci1; ci1 = ci2; ci2 = ti; }
        if (cd1 < cd0) { float t = cd0; cd0 = cd1; cd1 = t; int ti = ci0; ci0 = ci1; ci1 = ti; }
    }

    // 16 rounds of wave-wide min extraction
    int nb[KNN];
    #pragma unroll
    for (int rnd = 0; rnd < KNN; ++rnd) {
        float wd = cd0;
        int   wi = ci0;
        #pragma unroll
        for (int off = 32; off > 0; off >>= 1) {
            float od = __shfl_xor(wd, off, 64);
            int   oi = __shfl_xor(wi, off, 64);
            bool take = (od < wd) || (od == wd && oi < wi);
            wd = take ? od : wd;
            wi = take ? oi : wi;
        }
        nb[rnd] = wi;
        bool own = ((wi & 63) == lane);
        cd0 = own ? cd1 : cd0;  ci0 = own ? ci1 : ci0;
        cd1 = own ? cd2 : cd1;  ci1 = own ? ci2 : ci1;
        cd2 = own ? __builtin_inff() : cd2;
    }

    // ---- message + max-aggregate; lane handles channel c = lane&15
    const int c = lane & 15;
    float cic = s_b[c];
    #pragma unroll
    for (int r = 0; r < HID; ++r) cic += xi[r] * s_dw[r * HID + c];

    float acc = -__builtin_inff();
    #pragma unroll
    for (int n = 0; n < KNN; ++n) {
        float m = cic + s_y[nb[n] * LDW + c];
        m = m > 0.0f ? m : expm1f(m);
        acc = fmaxf(acc, m);
    }

    if (!POOL) {
        if (lane < HID)
            out_feats[(size_t)(g * NDST + drow) * HID + c] = acc;
    } else {
        if (lane < HID) atomicAdd(&s_pool[c], acc);
        __syncthreads();
        if (tid < HID) atomicAdd(&pool_out[g * HID + tid], s_pool[tid]);
    }
}

// conv1 (lc->lc) and conv2 (lc->ts) are independent -> one fat dispatch.
#define C1_BLOCKS (NB * (LCG / 8))   // 1536
#define C2_BLOCKS (NB * (TSG / 8))   // 1024
__global__ __launch_bounds__(512) void edgeconv12_kernel(
    const float* __restrict__ lc_enc, const float* __restrict__ ts_enc,
    const float* __restrict__ cw, const float* __restrict__ cb,
    float* __restrict__ feats1, float* __restrict__ feats2)
{
    extern __shared__ float smem[];
    if (blockIdx.x < C1_BLOCKS)
        edgeconv_impl<LCG, LCG, false>(smem, blockIdx.x, lc_enc, lc_enc, cw, cb, feats1, nullptr);
    else
        edgeconv_impl<LCG, TSG, false>(smem, blockIdx.x - C1_BLOCKS, lc_enc, ts_enc, cw, cb, feats2, nullptr);
}

__global__ __launch_bounds__(512) void edgeconv3_kernel(
    const float* __restrict__ feats1, const float* __restrict__ feats2,
    const float* __restrict__ cw, const float* __restrict__ cb,
    float* __restrict__ pooled)
{
    extern __shared__ float smem[];
    edgeconv_impl<LCG, TSG, true>(smem, blockIdx.x, feats1, feats2, cw, cb, nullptr, pooled);
}

// ---------------------------------------------------------------- head MLP
// One block per graph, lane-coalesced weight loads, LDS relay between
// layers. Accumulation order identical to v2 (r ascending) => bit-exact.
__global__ __launch_bounds__(64) void head_kernel(
    const float* __restrict__ pooled,   // SUMS over 128 rows per graph
    const float* __restrict__ w1, const float* __restrict__ b1,
    const float* __restrict__ w2, const float* __restrict__ b2,
    const float* __restrict__ w3, const float* __restrict__ b3,
    const float* __restrict__ w4, const float* __restrict__ b4,
    const float* __restrict__ w5, const float* __restrict__ b5,
    float* __restrict__ out)
{
    const int g = blockIdx.x;
    const int lane = threadIdx.x;
    __shared__ float sp[HID];
    __shared__ float sh1[64];
    __shared__ float sh2[32];
    __shared__ float sh3[8];
    __shared__ float sh4[4];

    if (lane < HID) sp[lane] = pooled[g * HID + lane] * (1.0f / (float)TSG);
    __syncthreads();

    {   // layer 1: 64 outputs, one per lane; w1 loads coalesced
        float s = b1[lane];
        #pragma unroll
        for (int r = 0; r < HID; ++r) s += sp[r] * w1[r * 64 + lane];
        sh1[lane] = eluf(s);
    }
    __syncthreads();
    if (lane < 32) {
        float s = b2[lane];
        #pragma unroll
        for (int r = 0; r < 64; ++r) s += sh1[r] * w2[r * 32 + lane];
        sh2[lane] = eluf(s);
    }
    __syncthreads();
    if (lane < 8) {
        float s = b3[lane];
        #pragma unroll
        for (int r = 0; r < 32; ++r) s += sh2[r] * w3[r * 8 + lane];
        sh3[lane] = eluf(s);
    }
    __syncthreads();
    if (lane < 4) {
        float s = b4[lane];
        #pragma unroll
        for (int r = 0; r < 8; ++r) s += sh3[r] * w4[r * 4 + lane];
        sh4[lane] = eluf(s);
    }
    __syncthreads();
    if (lane == 0) {
        float s = b5[0];
        #pragma unroll
        for (int r = 0; r < 4; ++r) s += sh4[r] * w5[r];
        out[g] = s;
        out[NB + g] = (float)g;   // batch_out = arange(B)
    }
}

// ---------------------------------------------------------------- launch
extern "C" void kernel_launch(void* const* d_in, const int* in_sizes, int n_in,
                              void* d_out, int out_size, void* d_ws, size_t ws_size,
                              hipStream_t stream) {
    const float* x_ts  = (const float*)d_in[0];
    const float* x_lc  = (const float*)d_in[1];
    // d_in[2], d_in[3]: batch arrays — contiguous repeat(arange(64)), layout hard-coded
    const float* ts_w1 = (const float*)d_in[4];
    const float* ts_b1 = (const float*)d_in[5];
    const float* ts_w2 = (const float*)d_in[6];
    const float* ts_b2 = (const float*)d_in[7];
    const float* lc_w1 = (const float*)d_in[8];
    const float* lc_b1 = (const float*)d_in[9];
    const float* lc_w2 = (const float*)d_in[10];
    const float* lc_b2 = (const float*)d_in[11];
    const float* cw    = (const float*)d_in[12];
    const float* cb    = (const float*)d_in[13];
    const float* ow1   = (const float*)d_in[14];
    const float* ob1   = (const float*)d_in[15];
    const float* ow2   = (const float*)d_in[16];
    const float* ob2   = (const float*)d_in[17];
    const float* ow3   = (const float*)d_in[18];
    const float* ob3   = (const float*)d_in[19];
    const float* ow4   = (const float*)d_in[20];
    const float* ob4   = (const float*)d_in[21];
    const float* ow5   = (const float*)d_in[22];
    const float* ob5   = (const float*)d_in[23];
    float* out = (float*)d_out;

    float* ws = (float*)d_ws;
    float* ts_enc = ws;                       // 8192*16  = 131072
    float* lc_enc = ws + 131072;              // 12288*16 = 196608
    float* feats1 = ws + 327680;              // 12288*16 = 196608
    float* feats2 = ws + 524288;              // 8192*16  = 131072
    float* pooled = ws + 655360;              // 64*16    = 1024

    encode_kernel<<<(NTS + NLC) / 256, 256, 0, stream>>>(
        x_ts, x_lc, ts_w1, ts_b1, ts_w2, ts_b2, lc_w1, lc_b1, lc_w2, lc_b2,
        ts_enc, lc_enc, pooled);

    // conv1 + conv2 fused into one fat dispatch (independent)
    edgeconv12_kernel<<<C1_BLOCKS + C2_BLOCKS, 512, CONV_SMEM_BYTES, stream>>>(
        lc_enc, ts_enc, cw, cb, feats1, feats2);

    // conv3: feats1 src, feats2 dst, fused mean-pool via atomics
    edgeconv3_kernel<<<C2_BLOCKS, 512, CONV_SMEM_BYTES, stream>>>(
        feats1, feats2, cw, cb, pooled);

    head_kernel<<<NB, 64, 0, stream>>>(
        pooled, ow1, ob1, ow2, ob2, ow3, ob3, ow4, ob4, ow5, ob5, out);
}

// Round 4
// 196.347 us; speedup vs baseline: 2.2426x; 1.0499x over previous
//
#include <hip/hip_runtime.h>
#include <math.h>

#define HID 16
#define KNN 16
#define NB 64          // graphs
#define NTS 8192
#define NLC 12288
#define TSG 128        // ts rows per graph
#define LCG 192        // lc rows per graph

__device__ __forceinline__ float eluf(float x) {
    return x > 0.0f ? x : expm1f(x);
}

// monotone map float -> uint32 (total order matches float <, incl. negatives)
__device__ __forceinline__ unsigned int f2ord(float f) {
    unsigned int b = __float_as_uint(f);
    return b ^ (((int)b >> 31) | 0x80000000u);
}

// ---------------------------------------------------------------- encoders
// Per-row 2-layer MLP with weights staged in LDS. For lc rows additionally
// emits y_lc = lc_enc @ conv_W2 and n_lc = ||row||^2 (hoisted out of the
// conv kernels, which used to recompute them 24x/16x per graph).
// Blocks 0..31 -> ts rows, 32..79 -> lc rows. Also zeroes `pooled`.
__global__ __launch_bounds__(256) void encode_kernel(
    const float* __restrict__ x_ts, const float* __restrict__ x_lc,
    const float* __restrict__ ts_w1, const float* __restrict__ ts_b1,
    const float* __restrict__ ts_w2, const float* __restrict__ ts_b2,
    const float* __restrict__ lc_w1, const float* __restrict__ lc_b1,
    const float* __restrict__ lc_w2, const float* __restrict__ lc_b2,
    const float* __restrict__ cw,
    float* __restrict__ ts_enc, float* __restrict__ lc_enc,
    float* __restrict__ y_lc, float* __restrict__ n_lc,
    float* __restrict__ pooled)
{
    __shared__ float sw1[6 * HID];
    __shared__ float sw2[HID * HID];
    __shared__ float scw2[HID * HID];   // conv W2 (lc blocks only)
    __shared__ float sb1[HID];
    __shared__ float sb2[HID];

    const int tid = threadIdx.x;
    const int t = blockIdx.x * 256 + tid;
    if (t < NB * HID) pooled[t] = 0.0f;   // zero pool accumulator (0xAA-poisoned)

    const bool is_ts = (blockIdx.x < NTS / 256);
    const float* w1 = is_ts ? ts_w1 : lc_w1;
    const float* b1 = is_ts ? ts_b1 : lc_b1;
    const float* w2 = is_ts ? ts_w2 : lc_w2;
    const float* b2 = is_ts ? ts_b2 : lc_b2;
    const int in_dim = is_ts ? 6 : 5;

    if (tid < in_dim * HID) sw1[tid] = w1[tid];
    if (tid < HID * HID)    sw2[tid] = w2[tid];
    if (!is_ts && tid < HID * HID) scw2[tid] = cw[HID * HID + tid];
    if (tid < HID)          { sb1[tid] = b1[tid]; sb2[tid] = b2[tid]; }
    __syncthreads();

    const float* x;
    float* outp;
    int r = 0;
    if (is_ts) { x = x_ts + (size_t)t * 6;          outp = ts_enc + (size_t)t * HID; }
    else       { r = t - NTS; x = x_lc + (size_t)r * 5; outp = lc_enc + (size_t)r * HID; }

    float xin[6];
    for (int k = 0; k < in_dim; ++k) xin[k] = x[k];
    float h[HID];
    #pragma unroll
    for (int c = 0; c < HID; ++c) {
        float s = sb1[c];
        for (int k = 0; k < in_dim; ++k) s += xin[k] * sw1[k * HID + c];
        h[c] = eluf(s);
    }
    float o[HID];
    #pragma unroll
    for (int c = 0; c < HID; ++c) {
        float s = sb2[c];
        #pragma unroll
        for (int k = 0; k < HID; ++k) s += h[k] * sw2[k * HID + c];
        o[c] = eluf(s);
    }
    float4* o4 = reinterpret_cast<float4*>(outp);
    o4[0] = make_float4(o[0],  o[1],  o[2],  o[3]);
    o4[1] = make_float4(o[4],  o[5],  o[6],  o[7]);
    o4[2] = make_float4(o[8],  o[9],  o[10], o[11]);
    o4[3] = make_float4(o[12], o[13], o[14], o[15]);

    if (!is_ts) {
        float nv = 0.f;
        #pragma unroll
        for (int c = 0; c < HID; ++c) nv += o[c] * o[c];   // c ascending (exact-zero self-dist)
        float y[HID];
        #pragma unroll
        for (int c = 0; c < HID; ++c) {
            float s = 0.f;
            #pragma unroll
            for (int k = 0; k < HID; ++k) s += o[k] * scw2[k * HID + c];
            y[c] = s;
        }
        float4* y4 = reinterpret_cast<float4*>(y_lc + (size_t)r * HID);
        y4[0] = make_float4(y[0],  y[1],  y[2],  y[3]);
        y4[1] = make_float4(y[4],  y[5],  y[6],  y[7]);
        y4[2] = make_float4(y[8],  y[9],  y[10], y[11]);
        y4[3] = make_float4(y[12], y[13], y[14], y[15]);
        n_lc[r] = nv;
    }
}

// ------------------------------------------------------------ edge conv
// ONE WAVE PER DST ROW; block = 512 threads = 8 dst rows of one graph.
// y = src@W2 and ||src||^2 arrive PRECOMPUTED (encode / conv1 epilogue).
// Each lane keeps its 3 src rows {l, l+64, l+128} in REGISTERS (distance
// dots never need other lanes' rows) — no s_src LDS, no phase-1.
// Top-16: (d, idx) packed into one sortable u64; 16 rounds of 6-step
// butterfly u64-min (matches top_k lexicographic tie-break); the message
// FMA + running max are fused into the extraction loop; ELU applied ONCE
// after the max (elu is monotone => identical to max-of-elus).
#define CONV_SMEM_FLOATS (LCG * HID + 2 * HID * HID + 2 * HID)
#define CONV_SMEM_BYTES  (CONV_SMEM_FLOATS * 4)

template<int NSRC, int NDST, bool POOL, bool EPI>
__device__ __forceinline__ void edgeconv_impl(
    float* __restrict__ smem, int bid,
    const float* __restrict__ src, const float* __restrict__ src_y,
    const float* __restrict__ src_n, const float* __restrict__ dst,
    const float* __restrict__ cw, const float* __restrict__ cb,
    float* __restrict__ out_feats, float* __restrict__ out_y,
    float* __restrict__ out_n, float* __restrict__ pool_out)
{
    constexpr int RPB = 8;              // dst rows (waves) per block
    constexpr int BPG = NDST / RPB;     // blocks per graph
    float* s_y    = smem;                        // NSRC*HID (16-wide: reads are wave-uniform broadcasts)
    float* s_dw   = s_y + NSRC * HID;            // 256  (W1 - W2)
    float* s_w2   = s_dw + HID * HID;            // 256  (EPI only)
    float* s_b    = s_w2 + HID * HID;            // 16
    float* s_pool = s_b + HID;                   // 16

    const int tid  = threadIdx.x;
    const int lane = tid & 63;
    const int wave = tid >> 6;
    const int g      = bid / BPG;
    const int rowblk = bid % BPG;

    // ---- stage weights + y (coalesced float4)
    if (tid < HID * HID) {
        float w1v = cw[tid];
        float w2v = cw[HID * HID + tid];
        s_dw[tid] = w1v - w2v;
        if (EPI) s_w2[tid] = w2v;
    }
    if (tid < HID) s_b[tid] = cb[tid];
    if (POOL && tid < HID) s_pool[tid] = 0.0f;
    {
        const float4* gy = reinterpret_cast<const float4*>(src_y + (size_t)(g * NSRC) * HID);
        float4* sy4 = reinterpret_cast<float4*>(s_y);
        for (int i = tid; i < NSRC * HID / 4; i += 512) sy4[i] = gy[i];
    }

    // ---- own src rows + norms -> registers (overlaps with staging)
    float rw[3][HID];
    float rn[3];
    #pragma unroll
    for (int k = 0; k < 3; ++k) {
        const float4* rp = reinterpret_cast<const float4*>(src + (size_t)(g * NSRC + lane + 64 * k) * HID);
        float4 a = rp[0], b = rp[1], c4 = rp[2], e = rp[3];
        rw[k][0] = a.x;  rw[k][1] = a.y;  rw[k][2]  = a.z;  rw[k][3]  = a.w;
        rw[k][4] = b.x;  rw[k][5] = b.y;  rw[k][6]  = b.z;  rw[k][7]  = b.w;
        rw[k][8] = c4.x; rw[k][9] = c4.y; rw[k][10] = c4.z; rw[k][11] = c4.w;
        rw[k][12] = e.x; rw[k][13] = e.y; rw[k][14] = e.z;  rw[k][15] = e.w;
        rn[k] = src_n[g * NSRC + lane + 64 * k];
    }

    // ---- my wave's dst row
    const int drow = rowblk * RPB + wave;
    const float4* d4 = reinterpret_cast<const float4*>(dst + (size_t)(g * NDST + drow) * HID);
    float xi[HID];
    {
        float4 a = d4[0], b = d4[1], c4 = d4[2], e = d4[3];
        xi[0] = a.x;  xi[1] = a.y;  xi[2]  = a.z;  xi[3]  = a.w;
        xi[4] = b.x;  xi[5] = b.y;  xi[6]  = b.z;  xi[7]  = b.w;
        xi[8] = c4.x; xi[9] = c4.y; xi[10] = c4.z; xi[11] = c4.w;
        xi[12] = e.x; xi[13] = e.y; xi[14] = e.z;  xi[15] = e.w;
    }
    float nd = 0.f;
    #pragma unroll
    for (int c = 0; c < HID; ++c) nd += xi[c] * xi[c];

    // ---- 3 candidates/lane, packed u64 keys, sorted (register-only)
    unsigned long long k0, k1, k2;
    {
        unsigned long long kk[3];
        #pragma unroll
        for (int k = 0; k < 3; ++k) {
            float dot = 0.f;
            #pragma unroll
            for (int c = 0; c < HID; ++c) dot += xi[c] * rw[k][c];
            float d = nd - 2.0f * dot + rn[k];
            kk[k] = ((unsigned long long)f2ord(d) << 32) | (unsigned int)(lane + 64 * k);
        }
        k0 = kk[0]; k1 = kk[1]; k2 = kk[2];
        if (k1 < k0) { unsigned long long t = k0; k0 = k1; k1 = t; }
        if (k2 < k1) { unsigned long long t = k1; k1 = k2; k2 = t; }
        if (k1 < k0) { unsigned long long t = k0; k0 = k1; k1 = t; }
    }

    __syncthreads();   // s_y / s_dw ready

    // ci = b + xi @ (W1 - W2); lane handles channel c = lane & 15
    const int c = lane & 15;
    float cic = s_b[c];
    #pragma unroll
    for (int r = 0; r < HID; ++r) cic += xi[r] * s_dw[r * HID + c];

    // ---- 16 rounds of wave-wide u64-min extraction, message fused in
    float m = -__builtin_inff();
    #pragma unroll
    for (int rnd = 0; rnd < KNN; ++rnd) {
        unsigned long long k = k0;
        #pragma unroll
        for (int off = 32; off > 0; off >>= 1) {
            unsigned long long o = __shfl_xor(k, off, 64);
            if (o < k) k = o;
        }
        const int widx = (int)(unsigned int)k;         // winner src row (wave-uniform)
        m = fmaxf(m, cic + s_y[widx * HID + c]);       // raw pre-activation message
        const bool own = ((widx & 63) == lane);        // winner is owner's head
        k0 = own ? k1 : k0;
        k1 = own ? k2 : k1;
        k2 = own ? ~0ull : k2;
    }
    const float f = eluf(m);   // elu once: max(elu(z)) == elu(max(z))

    if (POOL) {
        if (lane < HID) atomicAdd(&s_pool[c], f);
        __syncthreads();
        if (tid < HID) atomicAdd(&pool_out[g * HID + tid], s_pool[tid]);
    } else {
        const int grow = g * NDST + drow;
        if (lane < HID) out_feats[(size_t)grow * HID + c] = f;
        if (EPI) {
            // y_f1 = feats1 @ W2 and n_f1 = ||feats1||^2, via lane broadcasts
            float yv = 0.f, nv = 0.f;
            #pragma unroll
            for (int r = 0; r < HID; ++r) {
                float fr = __shfl(f, r, 64);   // lane r holds channel r
                yv += fr * s_w2[r * HID + c];
                nv += fr * fr;                 // c... r ascending (matches encode)
            }
            if (lane < HID) out_y[(size_t)grow * HID + c] = yv;
            if (lane == 0)  out_n[grow] = nv;
        }
    }
}

// conv1 (lc->lc, emits y/n for conv3) and conv2 (lc->ts): independent -> one dispatch.
#define C1_BLOCKS (NB * (LCG / 8))   // 1536
#define C2_BLOCKS (NB * (TSG / 8))   // 1024
__global__ __launch_bounds__(512) void edgeconv12_kernel(
    const float* __restrict__ lc_enc, const float* __restrict__ y_lc,
    const float* __restrict__ n_lc, const float* __restrict__ ts_enc,
    const float* __restrict__ cw, const float* __restrict__ cb,
    float* __restrict__ feats1, float* __restrict__ y_f1, float* __restrict__ n_f1,
    float* __restrict__ feats2)
{
    extern __shared__ float smem[];
    if (blockIdx.x < C1_BLOCKS)
        edgeconv_impl<LCG, LCG, false, true>(smem, blockIdx.x, lc_enc, y_lc, n_lc,
                                             lc_enc, cw, cb, feats1, y_f1, n_f1, nullptr);
    else
        edgeconv_impl<LCG, TSG, false, false>(smem, blockIdx.x - C1_BLOCKS, lc_enc, y_lc, n_lc,
                                              ts_enc, cw, cb, feats2, nullptr, nullptr, nullptr);
}

__global__ __launch_bounds__(512) void edgeconv3_kernel(
    const float* __restrict__ feats1, const float* __restrict__ y_f1,
    const float* __restrict__ n_f1, const float* __restrict__ feats2,
    const float* __restrict__ cw, const float* __restrict__ cb,
    float* __restrict__ pooled)
{
    extern __shared__ float smem[];
    edgeconv_impl<LCG, TSG, true, false>(smem, blockIdx.x, feats1, y_f1, n_f1,
                                         feats2, cw, cb, nullptr, nullptr, nullptr, pooled);
}

// ---------------------------------------------------------------- head MLP
__global__ __launch_bounds__(64) void head_kernel(
    const float* __restrict__ pooled,   // SUMS over 128 rows per graph
    const float* __restrict__ w1, const float* __restrict__ b1,
    const float* __restrict__ w2, const float* __restrict__ b2,
    const float* __restrict__ w3, const float* __restrict__ b3,
    const float* __restrict__ w4, const float* __restrict__ b4,
    const float* __restrict__ w5, const float* __restrict__ b5,
    float* __restrict__ out)
{
    const int g = blockIdx.x;
    const int lane = threadIdx.x;
    __shared__ float sp[HID];
    __shared__ float sh1[64];
    __shared__ float sh2[32];
    __shared__ float sh3[8];
    __shared__ float sh4[4];

    if (lane < HID) sp[lane] = pooled[g * HID + lane] * (1.0f / (float)TSG);
    __syncthreads();

    {
        float s = b1[lane];
        #pragma unroll
        for (int r = 0; r < HID; ++r) s += sp[r] * w1[r * 64 + lane];
        sh1[lane] = eluf(s);
    }
    __syncthreads();
    if (lane < 32) {
        float s = b2[lane];
        #pragma unroll
        for (int r = 0; r < 64; ++r) s += sh1[r] * w2[r * 32 + lane];
        sh2[lane] = eluf(s);
    }
    __syncthreads();
    if (lane < 8) {
        float s = b3[lane];
        #pragma unroll
        for (int r = 0; r < 32; ++r) s += sh2[r] * w3[r * 8 + lane];
        sh3[lane] = eluf(s);
    }
    __syncthreads();
    if (lane < 4) {
        float s = b4[lane];
        #pragma unroll
        for (int r = 0; r < 8; ++r) s += sh3[r] * w4[r * 4 + lane];
        sh4[lane] = eluf(s);
    }
    __syncthreads();
    if (lane == 0) {
        float s = b5[0];
        #pragma unroll
        for (int r = 0; r < 4; ++r) s += sh4[r] * w5[r];
        out[g] = s;
        out[NB + g] = (float)g;   // batch_out = arange(B)
    }
}

// ---------------------------------------------------------------- launch
extern "C" void kernel_launch(void* const* d_in, const int* in_sizes, int n_in,
                              void* d_out, int out_size, void* d_ws, size_t ws_size,
                              hipStream_t stream) {
    const float* x_ts  = (const float*)d_in[0];
    const float* x_lc  = (const float*)d_in[1];
    // d_in[2], d_in[3]: batch arrays — contiguous repeat(arange(64)), layout hard-coded
    const float* ts_w1 = (const float*)d_in[4];
    const float* ts_b1 = (const float*)d_in[5];
    const float* ts_w2 = (const float*)d_in[6];
    const float* ts_b2 = (const float*)d_in[7];
    const float* lc_w1 = (const float*)d_in[8];
    const float* lc_b1 = (const float*)d_in[9];
    const float* lc_w2 = (const float*)d_in[10];
    const float* lc_b2 = (const float*)d_in[11];
    const float* cw    = (const float*)d_in[12];
    const float* cb    = (const float*)d_in[13];
    const float* ow1   = (const float*)d_in[14];
    const float* ob1   = (const float*)d_in[15];
    const float* ow2   = (const float*)d_in[16];
    const float* ob2   = (const float*)d_in[17];
    const float* ow3   = (const float*)d_in[18];
    const float* ob3   = (const float*)d_in[19];
    const float* ow4   = (const float*)d_in[20];
    const float* ob4   = (const float*)d_in[21];
    const float* ow5   = (const float*)d_in[22];
    const float* ob5   = (const float*)d_in[23];
    float* out = (float*)d_out;

    float* ws = (float*)d_ws;
    float* ts_enc = ws;                       // 8192*16  = 131072
    float* lc_enc = ws + 131072;              // 12288*16 = 196608
    float* feats1 = ws + 327680;              // 12288*16 = 196608
    float* feats2 = ws + 524288;              // 8192*16  = 131072
    float* pooled = ws + 655360;              // 64*16    = 1024
    float* y_lc   = ws + 656384;              // 12288*16 = 196608
    float* n_lc   = ws + 852992;              // 12288
    float* y_f1   = ws + 865280;              // 12288*16 = 196608
    float* n_f1   = ws + 1061888;             // 12288    (end: 1074176 floats = 4.1 MB)

    encode_kernel<<<(NTS + NLC) / 256, 256, 0, stream>>>(
        x_ts, x_lc, ts_w1, ts_b1, ts_w2, ts_b2, lc_w1, lc_b1, lc_w2, lc_b2,
        cw, ts_enc, lc_enc, y_lc, n_lc, pooled);

    edgeconv12_kernel<<<C1_BLOCKS + C2_BLOCKS, 512, CONV_SMEM_BYTES, stream>>>(
        lc_enc, y_lc, n_lc, ts_enc, cw, cb, feats1, y_f1, n_f1, feats2);

    edgeconv3_kernel<<<C2_BLOCKS, 512, CONV_SMEM_BYTES, stream>>>(
        feats1, y_f1, n_f1, feats2, cw, cb, pooled);

    head_kernel<<<NB, 64, 0, stream>>>(
        pooled, ow1, ob1, ow2, ob2, ow3, ob3, ow4, ob4, ow5, ob5, out);
}

// Round 5
// 163.542 us; speedup vs baseline: 2.6924x; 1.2006x over previous
//
#include <hip/hip_runtime.h>
#include <math.h>

#define HID 16
#define KNN 16
#define NB 64          // graphs
#define NTS 8192
#define NLC 12288
#define TSG 128        // ts rows per graph
#define LCG 192        // lc rows per graph

__device__ __forceinline__ float eluf(float x) {
    return x > 0.0f ? x : expm1f(x);
}

// monotone map float -> uint32 (total order matches float <, incl. negatives)
__device__ __forceinline__ unsigned int f2ord(float f) {
    unsigned int b = __float_as_uint(f);
    return b ^ (((int)b >> 31) | 0x80000000u);
}

// ---------------------------------------------------------------- encoders
// Per-row 2-layer MLP with weights staged in LDS. For lc rows additionally
// emits y_lc = lc_enc @ conv_W2 and n_lc = ||row||^2 (hoisted out of the
// conv kernels). Blocks 0..31 -> ts rows, 32..79 -> lc. Also zeroes pooled.
__global__ __launch_bounds__(256) void encode_kernel(
    const float* __restrict__ x_ts, const float* __restrict__ x_lc,
    const float* __restrict__ ts_w1, const float* __restrict__ ts_b1,
    const float* __restrict__ ts_w2, const float* __restrict__ ts_b2,
    const float* __restrict__ lc_w1, const float* __restrict__ lc_b1,
    const float* __restrict__ lc_w2, const float* __restrict__ lc_b2,
    const float* __restrict__ cw,
    float* __restrict__ ts_enc, float* __restrict__ lc_enc,
    float* __restrict__ y_lc, float* __restrict__ n_lc,
    float* __restrict__ pooled)
{
    __shared__ float sw1[6 * HID];
    __shared__ float sw2[HID * HID];
    __shared__ float scw2[HID * HID];   // conv W2 (lc blocks only)
    __shared__ float sb1[HID];
    __shared__ float sb2[HID];

    const int tid = threadIdx.x;
    const int t = blockIdx.x * 256 + tid;
    if (t < NB * HID) pooled[t] = 0.0f;   // zero pool accumulator (0xAA-poisoned)

    const bool is_ts = (blockIdx.x < NTS / 256);
    const float* w1 = is_ts ? ts_w1 : lc_w1;
    const float* b1 = is_ts ? ts_b1 : lc_b1;
    const float* w2 = is_ts ? ts_w2 : lc_w2;
    const float* b2 = is_ts ? ts_b2 : lc_b2;
    const int in_dim = is_ts ? 6 : 5;

    if (tid < in_dim * HID) sw1[tid] = w1[tid];
    if (tid < HID * HID)    sw2[tid] = w2[tid];
    if (!is_ts && tid < HID * HID) scw2[tid] = cw[HID * HID + tid];
    if (tid < HID)          { sb1[tid] = b1[tid]; sb2[tid] = b2[tid]; }
    __syncthreads();

    const float* x;
    float* outp;
    int r = 0;
    if (is_ts) { x = x_ts + (size_t)t * 6;          outp = ts_enc + (size_t)t * HID; }
    else       { r = t - NTS; x = x_lc + (size_t)r * 5; outp = lc_enc + (size_t)r * HID; }

    float xin[6];
    for (int k = 0; k < in_dim; ++k) xin[k] = x[k];
    float h[HID];
    #pragma unroll
    for (int c = 0; c < HID; ++c) {
        float s = sb1[c];
        for (int k = 0; k < in_dim; ++k) s += xin[k] * sw1[k * HID + c];
        h[c] = eluf(s);
    }
    float o[HID];
    #pragma unroll
    for (int c = 0; c < HID; ++c) {
        float s = sb2[c];
        #pragma unroll
        for (int k = 0; k < HID; ++k) s += h[k] * sw2[k * HID + c];
        o[c] = eluf(s);
    }
    float4* o4 = reinterpret_cast<float4*>(outp);
    o4[0] = make_float4(o[0],  o[1],  o[2],  o[3]);
    o4[1] = make_float4(o[4],  o[5],  o[6],  o[7]);
    o4[2] = make_float4(o[8],  o[9],  o[10], o[11]);
    o4[3] = make_float4(o[12], o[13], o[14], o[15]);

    if (!is_ts) {
        float nv = 0.f;
        #pragma unroll
        for (int c = 0; c < HID; ++c) nv += o[c] * o[c];   // c ascending (exact-zero self-dist)
        float y[HID];
        #pragma unroll
        for (int c = 0; c < HID; ++c) {
            float s = 0.f;
            #pragma unroll
            for (int k = 0; k < HID; ++k) s += o[k] * scw2[k * HID + c];
            y[c] = s;
        }
        float4* y4 = reinterpret_cast<float4*>(y_lc + (size_t)r * HID);
        y4[0] = make_float4(y[0],  y[1],  y[2],  y[3]);
        y4[1] = make_float4(y[4],  y[5],  y[6],  y[7]);
        y4[2] = make_float4(y[8],  y[9],  y[10], y[11]);
        y4[3] = make_float4(y[12], y[13], y[14], y[15]);
        n_lc[r] = nv;
    }
}

// ------------------------------------------------------------ edge conv
// ONE WAVE PER DST ROW; block = 512 threads = 8 dst rows of one graph.
// y = src@W2 and ||src||^2 precomputed. Lane keeps its 3 src rows
// {l, l+64, l+128} in registers. Top-16 SET (order irrelevant since
// max_j(ci+y_j) = ci + max_j y_j, exact by fp-add monotonicity) found via
// BALLOT-RADIX SELECT: 32 MSB->LSB rounds on the ordered-u32 distance
// (pure VALU/SALU, no LDS-pipe shuffle chains), exact idx tie-break via a
// gated 8-bit index bisection -> reproduces top_k lexicographic semantics.
// Winner y rows then read as 16 INDEPENDENT ds_reads (one lgkmcnt drain).
#define CONV_SMEM_FLOATS (LCG * HID + 2 * HID * HID + 2 * HID)
#define CONV_SMEM_BYTES  (CONV_SMEM_FLOATS * 4)

template<int NSRC, int NDST, bool POOL, bool EPI>
__device__ __forceinline__ void edgeconv_impl(
    float* __restrict__ smem, int bid,
    const float* __restrict__ src, const float* __restrict__ src_y,
    const float* __restrict__ src_n, const float* __restrict__ dst,
    const float* __restrict__ cw, const float* __restrict__ cb,
    float* __restrict__ out_feats, float* __restrict__ out_y,
    float* __restrict__ out_n, float* __restrict__ pool_out)
{
    constexpr int RPB = 8;              // dst rows (waves) per block
    constexpr int BPG = NDST / RPB;     // blocks per graph
    float* s_y    = smem;                        // NSRC*HID
    float* s_dw   = s_y + NSRC * HID;            // 256  (W1 - W2)
    float* s_w2   = s_dw + HID * HID;            // 256  (EPI only)
    float* s_b    = s_w2 + HID * HID;            // 16
    float* s_pool = s_b + HID;                   // 16

    const int tid  = threadIdx.x;
    const int lane = tid & 63;
    const int wave = tid >> 6;
    const int g      = bid / BPG;
    const int rowblk = bid % BPG;

    // ---- stage weights + y (coalesced float4)
    if (tid < HID * HID) {
        float w1v = cw[tid];
        float w2v = cw[HID * HID + tid];
        s_dw[tid] = w1v - w2v;
        if (EPI) s_w2[tid] = w2v;
    }
    if (tid < HID) s_b[tid] = cb[tid];
    if (POOL && tid < HID) s_pool[tid] = 0.0f;
    {
        const float4* gy = reinterpret_cast<const float4*>(src_y + (size_t)(g * NSRC) * HID);
        float4* sy4 = reinterpret_cast<float4*>(s_y);
        for (int i = tid; i < NSRC * HID / 4; i += 512) sy4[i] = gy[i];
    }

    // ---- own src rows + norms -> registers
    float rw[3][HID];
    float rn[3];
    #pragma unroll
    for (int k = 0; k < 3; ++k) {
        const float4* rp = reinterpret_cast<const float4*>(src + (size_t)(g * NSRC + lane + 64 * k) * HID);
        float4 a = rp[0], b = rp[1], c4 = rp[2], e = rp[3];
        rw[k][0] = a.x;  rw[k][1] = a.y;  rw[k][2]  = a.z;  rw[k][3]  = a.w;
        rw[k][4] = b.x;  rw[k][5] = b.y;  rw[k][6]  = b.z;  rw[k][7]  = b.w;
        rw[k][8] = c4.x; rw[k][9] = c4.y; rw[k][10] = c4.z; rw[k][11] = c4.w;
        rw[k][12] = e.x; rw[k][13] = e.y; rw[k][14] = e.z;  rw[k][15] = e.w;
        rn[k] = src_n[g * NSRC + lane + 64 * k];
    }

    // ---- my wave's dst row
    const int drow = rowblk * RPB + wave;
    const float4* d4 = reinterpret_cast<const float4*>(dst + (size_t)(g * NDST + drow) * HID);
    float xi[HID];
    {
        float4 a = d4[0], b = d4[1], c4 = d4[2], e = d4[3];
        xi[0] = a.x;  xi[1] = a.y;  xi[2]  = a.z;  xi[3]  = a.w;
        xi[4] = b.x;  xi[5] = b.y;  xi[6]  = b.z;  xi[7]  = b.w;
        xi[8] = c4.x; xi[9] = c4.y; xi[10] = c4.z; xi[11] = c4.w;
        xi[12] = e.x; xi[13] = e.y; xi[14] = e.z;  xi[15] = e.w;
    }
    float nd = 0.f;
    #pragma unroll
    for (int c = 0; c < HID; ++c) nd += xi[c] * xi[c];

    // ---- 3 candidate distances as ordered-u32 (idx implicit: lane + 64k)
    unsigned int dk0, dk1, dk2;
    {
        unsigned int dk[3];
        #pragma unroll
        for (int k = 0; k < 3; ++k) {
            float dot = 0.f;
            #pragma unroll
            for (int c = 0; c < HID; ++c) dot += xi[c] * rw[k][c];
            dk[k] = f2ord(nd - 2.0f * dot + rn[k]);
        }
        dk0 = dk[0]; dk1 = dk[1]; dk2 = dk[2];
    }

    // ---- ballot-radix select of the 16th-smallest (dist, idx) key
    unsigned int p = 0;
    int k = KNN;
    for (int b = 31; b >= 0; --b) {
        unsigned int pb = p >> b;
        int cnt = __popcll(__ballot((dk0 >> b) == pb))
                + __popcll(__ballot((dk1 >> b) == pb))
                + __popcll(__ballot((dk2 >> b) == pb));
        if (k > cnt) { k -= cnt; p |= (1u << b); }
    }
    // p = dist of 16th key; k = how many of the dist==p class to include
    int cnt_eq = __popcll(__ballot(dk0 == p))
               + __popcll(__ballot(dk1 == p))
               + __popcll(__ballot(dk2 == p));
    unsigned int qi = 255u;              // idx cutoff within eq class
    if (cnt_eq != k) {                   // rare exact-dist tie at the boundary
        qi = 0;
        int kk = k;
        const unsigned int i0 = (unsigned)lane, i1 = (unsigned)(lane + 64), i2 = (unsigned)(lane + 128);
        for (int b = 7; b >= 0; --b) {
            unsigned int qb = qi >> b;
            int cnt = __popcll(__ballot(dk0 == p && (i0 >> b) == qb))
                    + __popcll(__ballot(dk1 == p && (i1 >> b) == qb))
                    + __popcll(__ballot(dk2 == p && (i2 >> b) == qb));
            if (kk > cnt) { kk -= cnt; qi |= (1u << b); }
        }
    }
    unsigned long long m0 = __ballot(dk0 < p || (dk0 == p && (unsigned)lane <= qi));
    unsigned long long m1 = __ballot(dk1 < p || (dk1 == p && (unsigned)(lane + 64) <= qi));
    unsigned long long m2 = __ballot(dk2 < p || (dk2 == p && (unsigned)(lane + 128) <= qi));
    // popc(m0)+popc(m1)+popc(m2) == 16 exactly

    __syncthreads();   // s_y / s_dw ready

    // ci = b + xi @ (W1 - W2); lane handles channel c = lane & 15
    const int c = lane & 15;
    float cic = s_b[c];
    #pragma unroll
    for (int r = 0; r < HID; ++r) cic += xi[r] * s_dw[r * HID + c];

    // ---- winner indices (SALU, wave-uniform), then 16 independent y reads
    int jarr[KNN];
    #pragma unroll
    for (int i = 0; i < KNN; ++i) {
        int j;
        if (m0)      { j = __builtin_ctzll(m0);       m0 &= m0 - 1; }
        else if (m1) { j = 64 + __builtin_ctzll(m1);  m1 &= m1 - 1; }
        else         { j = 128 + __builtin_ctzll(m2); m2 &= m2 - 1; }
        jarr[i] = j;
    }
    float yv[KNN];
    #pragma unroll
    for (int i = 0; i < KNN; ++i) yv[i] = s_y[jarr[i] * HID + c];
    float ym = yv[0];
    #pragma unroll
    for (int i = 1; i < KNN; ++i) ym = fmaxf(ym, yv[i]);

    const float f = eluf(cic + ym);   // == max_j elu(ci + y_j), exact

    if (POOL) {
        if (lane < HID) atomicAdd(&s_pool[c], f);
        __syncthreads();
        if (tid < HID) atomicAdd(&pool_out[g * HID + tid], s_pool[tid]);
    } else {
        const int grow = g * NDST + drow;
        if (lane < HID) out_feats[(size_t)grow * HID + c] = f;
        if (EPI) {
            // y_f1 = feats1 @ W2 and n_f1 = ||feats1||^2, via lane broadcasts
            float yvv = 0.f, nv = 0.f;
            #pragma unroll
            for (int r = 0; r < HID; ++r) {
                float fr = __shfl(f, r, 64);   // lane r holds channel r
                yvv += fr * s_w2[r * HID + c];
                nv += fr * fr;
            }
            if (lane < HID) out_y[(size_t)grow * HID + c] = yvv;
            if (lane == 0)  out_n[grow] = nv;
        }
    }
}

// conv1 (lc->lc, emits y/n for conv3) and conv2 (lc->ts): independent -> one dispatch.
#define C1_BLOCKS (NB * (LCG / 8))   // 1536
#define C2_BLOCKS (NB * (TSG / 8))   // 1024
__global__ __launch_bounds__(512) void edgeconv12_kernel(
    const float* __restrict__ lc_enc, const float* __restrict__ y_lc,
    const float* __restrict__ n_lc, const float* __restrict__ ts_enc,
    const float* __restrict__ cw, const float* __restrict__ cb,
    float* __restrict__ feats1, float* __restrict__ y_f1, float* __restrict__ n_f1,
    float* __restrict__ feats2)
{
    extern __shared__ float smem[];
    if (blockIdx.x < C1_BLOCKS)
        edgeconv_impl<LCG, LCG, false, true>(smem, blockIdx.x, lc_enc, y_lc, n_lc,
                                             lc_enc, cw, cb, feats1, y_f1, n_f1, nullptr);
    else
        edgeconv_impl<LCG, TSG, false, false>(smem, blockIdx.x - C1_BLOCKS, lc_enc, y_lc, n_lc,
                                              ts_enc, cw, cb, feats2, nullptr, nullptr, nullptr);
}

__global__ __launch_bounds__(512) void edgeconv3_kernel(
    const float* __restrict__ feats1, const float* __restrict__ y_f1,
    const float* __restrict__ n_f1, const float* __restrict__ feats2,
    const float* __restrict__ cw, const float* __restrict__ cb,
    float* __restrict__ pooled)
{
    extern __shared__ float smem[];
    edgeconv_impl<LCG, TSG, true, false>(smem, blockIdx.x, feats1, y_f1, n_f1,
                                         feats2, cw, cb, nullptr, nullptr, nullptr, pooled);
}

// ---------------------------------------------------------------- head MLP
__global__ __launch_bounds__(64) void head_kernel(
    const float* __restrict__ pooled,   // SUMS over 128 rows per graph
    const float* __restrict__ w1, const float* __restrict__ b1,
    const float* __restrict__ w2, const float* __restrict__ b2,
    const float* __restrict__ w3, const float* __restrict__ b3,
    const float* __restrict__ w4, const float* __restrict__ b4,
    const float* __restrict__ w5, const float* __restrict__ b5,
    float* __restrict__ out)
{
    const int g = blockIdx.x;
    const int lane = threadIdx.x;
    __shared__ float sp[HID];
    __shared__ float sh1[64];
    __shared__ float sh2[32];
    __shared__ float sh3[8];
    __shared__ float sh4[4];

    if (lane < HID) sp[lane] = pooled[g * HID + lane] * (1.0f / (float)TSG);
    __syncthreads();

    {
        float s = b1[lane];
        #pragma unroll
        for (int r = 0; r < HID; ++r) s += sp[r] * w1[r * 64 + lane];
        sh1[lane] = eluf(s);
    }
    __syncthreads();
    if (lane < 32) {
        float s = b2[lane];
        #pragma unroll
        for (int r = 0; r < 64; ++r) s += sh1[r] * w2[r * 32 + lane];
        sh2[lane] = eluf(s);
    }
    __syncthreads();
    if (lane < 8) {
        float s = b3[lane];
        #pragma unroll
        for (int r = 0; r < 32; ++r) s += sh2[r] * w3[r * 8 + lane];
        sh3[lane] = eluf(s);
    }
    __syncthreads();
    if (lane < 4) {
        float s = b4[lane];
        #pragma unroll
        for (int r = 0; r < 8; ++r) s += sh3[r] * w4[r * 4 + lane];
        sh4[lane] = eluf(s);
    }
    __syncthreads();
    if (lane == 0) {
        float s = b5[0];
        #pragma unroll
        for (int r = 0; r < 4; ++r) s += sh4[r] * w5[r];
        out[g] = s;
        out[NB + g] = (float)g;   // batch_out = arange(B)
    }
}

// ---------------------------------------------------------------- launch
extern "C" void kernel_launch(void* const* d_in, const int* in_sizes, int n_in,
                              void* d_out, int out_size, void* d_ws, size_t ws_size,
                              hipStream_t stream) {
    const float* x_ts  = (const float*)d_in[0];
    const float* x_lc  = (const float*)d_in[1];
    // d_in[2], d_in[3]: batch arrays — contiguous repeat(arange(64)), layout hard-coded
    const float* ts_w1 = (const float*)d_in[4];
    const float* ts_b1 = (const float*)d_in[5];
    const float* ts_w2 = (const float*)d_in[6];
    const float* ts_b2 = (const float*)d_in[7];
    const float* lc_w1 = (const float*)d_in[8];
    const float* lc_b1 = (const float*)d_in[9];
    const float* lc_w2 = (const float*)d_in[10];
    const float* lc_b2 = (const float*)d_in[11];
    const float* cw    = (const float*)d_in[12];
    const float* cb    = (const float*)d_in[13];
    const float* ow1   = (const float*)d_in[14];
    const float* ob1   = (const float*)d_in[15];
    const float* ow2   = (const float*)d_in[16];
    const float* ob2   = (const float*)d_in[17];
    const float* ow3   = (const float*)d_in[18];
    const float* ob3   = (const float*)d_in[19];
    const float* ow4   = (const float*)d_in[20];
    const float* ob4   = (const float*)d_in[21];
    const float* ow5   = (const float*)d_in[22];
    const float* ob5   = (const float*)d_in[23];
    float* out = (float*)d_out;

    float* ws = (float*)d_ws;
    float* ts_enc = ws;                       // 8192*16  = 131072
    float* lc_enc = ws + 131072;              // 12288*16 = 196608
    float* feats1 = ws + 327680;              // 12288*16 = 196608
    float* feats2 = ws + 524288;              // 8192*16  = 131072
    float* pooled = ws + 655360;              // 64*16    = 1024
    float* y_lc   = ws + 656384;              // 12288*16 = 196608
    float* n_lc   = ws + 852992;              // 12288
    float* y_f1   = ws + 865280;              // 12288*16 = 196608
    float* n_f1   = ws + 1061888;             // 12288    (end: 1074176 floats = 4.1 MB)

    encode_kernel<<<(NTS + NLC) / 256, 256, 0, stream>>>(
        x_ts, x_lc, ts_w1, ts_b1, ts_w2, ts_b2, lc_w1, lc_b1, lc_w2, lc_b2,
        cw, ts_enc, lc_enc, y_lc, n_lc, pooled);

    edgeconv12_kernel<<<C1_BLOCKS + C2_BLOCKS, 512, CONV_SMEM_BYTES, stream>>>(
        lc_enc, y_lc, n_lc, ts_enc, cw, cb, feats1, y_f1, n_f1, feats2);

    edgeconv3_kernel<<<C2_BLOCKS, 512, CONV_SMEM_BYTES, stream>>>(
        feats1, y_f1, n_f1, feats2, cw, cb, pooled);

    head_kernel<<<NB, 64, 0, stream>>>(
        pooled, ow1, ob1, ow2, ob2, ow3, ob3, ow4, ob4, ow5, ob5, out);
}